// Round 1
// baseline (295.248 us; speedup 1.0000x reference)
//
#include <hip/hip_runtime.h>

// Problem constants (from reference): B=16, S=4096, D=256, MAXDUR=8
#define BATCH 16
#define SEQ   4096
#define DIM   256

#define SCATTER_BLOCKS (BATCH * SEQ / 4)   // 4 waves/block, 1 wave per source row
#define TAILC 128                          // tail-zero blocks per batch

// ---------------------------------------------------------------------------
// Kernel A: per-batch inclusive scan of durations -> csum[B*S], totals[B]
// One block per batch; 1024 threads * 4 elements = 4096.
// ---------------------------------------------------------------------------
__global__ __launch_bounds__(1024) void scan_kernel(const int* __restrict__ dims,
                                                    int* __restrict__ csum,
                                                    int* __restrict__ totals) {
    __shared__ int wsum[16];
    const int b    = blockIdx.x;
    const int tid  = threadIdx.x;      // 0..1023
    const int lane = tid & 63;
    const int wave = tid >> 6;         // 0..15

    // 4 consecutive durations per thread (int4, 16B aligned)
    const int4 dv = ((const int4*)(dims + b * SEQ))[tid];
    const int p0 = dv.x;
    const int p1 = p0 + dv.y;
    const int p2 = p1 + dv.z;
    const int p3 = p2 + dv.w;          // thread-local inclusive sums
    int v = p3;                        // thread total

    // wave-level inclusive scan of thread totals (64 lanes)
    #pragma unroll
    for (int off = 1; off < 64; off <<= 1) {
        int n = __shfl_up(v, off, 64);
        if (lane >= off) v += n;
    }
    if (lane == 63) wsum[wave] = v;    // wave total
    __syncthreads();

    if (tid == 0) {                    // serial exclusive scan over 16 wave totals
        int run = 0;
        #pragma unroll
        for (int i = 0; i < 16; ++i) { int t = wsum[i]; wsum[i] = run; run += t; }
        totals[b] = run;               // full batch total
    }
    __syncthreads();

    const int excl = wsum[wave] + (v - p3);   // block-exclusive prefix of this thread
    int4 o;
    o.x = excl + p0; o.y = excl + p1; o.z = excl + p2; o.w = excl + p3;
    ((int4*)(csum + b * SEQ))[tid] = o;
}

// ---------------------------------------------------------------------------
// Kernel B: scatter-expand + tail zero-fill.
// Blocks [0, SCATTER_BLOCKS): one wave per source row (b,s). Reads the
//   256-float row once (float4/lane) and stores it d times to consecutive
//   output rows [csum[s-1], csum[s]).
// Blocks [SCATTER_BLOCKS, +B*TAILC): zero rows [totals[b], T).
// ---------------------------------------------------------------------------
__global__ __launch_bounds__(256) void expand_kernel(const float* __restrict__ x,
                                                     const int* __restrict__ csum,
                                                     const int* __restrict__ totals,
                                                     float* __restrict__ out,
                                                     int T) {
    const int lane = threadIdx.x & 63;
    const int wave = threadIdx.x >> 6;

    if (blockIdx.x < SCATTER_BLOCKS) {
        const int wv  = blockIdx.x * 4 + wave;    // global source-row id, 0..B*S-1
        const int b   = wv >> 12;                 // / SEQ
        const int s   = wv & (SEQ - 1);
        const int end   = csum[b * SEQ + s];
        const int start = (s == 0) ? 0 : csum[b * SEQ + s - 1];
        if (end <= start) return;                 // duration 0

        const float4 row = ((const float4*)(x + (size_t)(b * SEQ + s) * DIM))[lane];
        float4* dst = (float4*)(out + ((size_t)b * T + start) * DIM) + lane;
        for (int t = start; t < end; ++t) {       // d <= 7 consecutive row stores
            *dst = row;
            dst += DIM / 4;
        }
    } else {
        const int idx   = blockIdx.x - SCATTER_BLOCKS;
        const int b     = idx / TAILC;
        const int chunk = idx % TAILC;
        const int t0    = totals[b];
        const float4 z  = make_float4(0.f, 0.f, 0.f, 0.f);
        // TAILC blocks * 4 waves stride over tail rows of batch b
        for (int t = t0 + chunk * 4 + wave; t < T; t += TAILC * 4) {
            float4* dst = (float4*)(out + ((size_t)b * T + t) * DIM) + lane;
            *dst = z;
        }
    }
}

extern "C" void kernel_launch(void* const* d_in, const int* in_sizes, int n_in,
                              void* d_out, int out_size, void* d_ws, size_t ws_size,
                              hipStream_t stream) {
    const float* x    = (const float*)d_in[0];   // [B,S,D] float32
    const int*   dims = (const int*)d_in[1];     // [B,S,1] int32
    float*       out  = (float*)d_out;           // [B,T,D] float32

    const int T = out_size / (BATCH * DIM);      // padded output length

    int* totals = (int*)d_ws;                    // B ints
    int* csum   = totals + 64;                   // 256B offset keeps 16B alignment

    scan_kernel<<<BATCH, 1024, 0, stream>>>(dims, csum, totals);
    expand_kernel<<<SCATTER_BLOCKS + BATCH * TAILC, 256, 0, stream>>>(
        x, csum, totals, out, T);
}

// Round 3
// 283.648 us; speedup vs baseline: 1.0409x; 1.0409x over previous
//
#include <hip/hip_runtime.h>

// Problem constants (from reference): B=16, S=4096, D=256, MAXDUR=8
#define BATCH 16
#define SEQ   4096
#define DIM   256

#define SCATTER_BLOCKS (BATCH * SEQ / 4)   // 4 waves/block, 1 wave per source row
#define TAILC 128                          // tail-zero blocks per batch

// native clang vector type — accepted by __builtin_nontemporal_{load,store}
typedef float f32x4 __attribute__((ext_vector_type(4)));

// ---------------------------------------------------------------------------
// Kernel A: per-batch inclusive scan of durations -> csum[B*S], totals[B]
// One block per batch; 1024 threads * 4 elements = 4096.
// ---------------------------------------------------------------------------
__global__ __launch_bounds__(1024) void scan_kernel(const int* __restrict__ dims,
                                                    int* __restrict__ csum,
                                                    int* __restrict__ totals) {
    __shared__ int wsum[16];
    const int b    = blockIdx.x;
    const int tid  = threadIdx.x;      // 0..1023
    const int lane = tid & 63;
    const int wave = tid >> 6;         // 0..15

    // 4 consecutive durations per thread (int4, 16B aligned)
    const int4 dv = ((const int4*)(dims + b * SEQ))[tid];
    const int p0 = dv.x;
    const int p1 = p0 + dv.y;
    const int p2 = p1 + dv.z;
    const int p3 = p2 + dv.w;          // thread-local inclusive sums
    int v = p3;                        // thread total

    // wave-level inclusive scan of thread totals (64 lanes)
    #pragma unroll
    for (int off = 1; off < 64; off <<= 1) {
        int n = __shfl_up(v, off, 64);
        if (lane >= off) v += n;
    }
    if (lane == 63) wsum[wave] = v;    // wave total
    __syncthreads();

    if (tid == 0) {                    // serial exclusive scan over 16 wave totals
        int run = 0;
        #pragma unroll
        for (int i = 0; i < 16; ++i) { int t = wsum[i]; wsum[i] = run; run += t; }
        totals[b] = run;               // full batch total
    }
    __syncthreads();

    const int excl = wsum[wave] + (v - p3);   // block-exclusive prefix of this thread
    int4 o;
    o.x = excl + p0; o.y = excl + p1; o.z = excl + p2; o.w = excl + p3;
    ((int4*)(csum + b * SEQ))[tid] = o;
}

// ---------------------------------------------------------------------------
// Kernel B: scatter-expand + tail zero-fill.
// Blocks [0, SCATTER_BLOCKS): one wave per source row (b,s). Reads the
//   256-float row once (f32x4/lane, nontemporal) and stores it cnt times to
//   consecutive output rows [csum[s-1], csum[s]) as 7 INDEPENDENT predicated
//   nontemporal stores (cnt is wave-uniform -> s_cbranch, all stores can be
//   in flight simultaneously).
// Blocks [SCATTER_BLOCKS, +B*TAILC): zero rows [totals[b], T).
// ---------------------------------------------------------------------------
__global__ __launch_bounds__(256) void expand_kernel(const float* __restrict__ x,
                                                     const int* __restrict__ csum,
                                                     const int* __restrict__ totals,
                                                     float* __restrict__ out,
                                                     int T) {
    const int lane = threadIdx.x & 63;
    const int wave = threadIdx.x >> 6;

    if (blockIdx.x < SCATTER_BLOCKS) {
        const int wv  = blockIdx.x * 4 + wave;    // global source-row id, 0..B*S-1
        const int b   = wv >> 12;                 // / SEQ
        const int s   = wv & (SEQ - 1);
        const int end   = csum[b * SEQ + s];
        const int start = (s == 0) ? 0 : csum[b * SEQ + s - 1];
        const int cnt   = end - start;            // 0..MAXDUR-1 (wave-uniform)
        if (cnt <= 0) return;

        const f32x4 row = __builtin_nontemporal_load(
            ((const f32x4*)(x + (size_t)(b * SEQ + s) * DIM)) + lane);
        f32x4* dst = (f32x4*)(out + ((size_t)b * T + start) * DIM) + lane;

        // MAXDUR-1 == 7 independent stores, predicated by wave-uniform cnt
        #pragma unroll
        for (int j = 0; j < 7; ++j) {
            if (j < cnt) __builtin_nontemporal_store(row, dst + j * (DIM / 4));
        }
        // safety net if durations ever exceed 7 (shouldn't for MAXDUR=8)
        for (int j = 7; j < cnt; ++j) {
            __builtin_nontemporal_store(row, dst + j * (DIM / 4));
        }
    } else {
        const int idx   = blockIdx.x - SCATTER_BLOCKS;
        const int b     = idx / TAILC;
        const int chunk = idx % TAILC;
        const int t0    = totals[b];
        const f32x4 z   = {0.f, 0.f, 0.f, 0.f};
        // TAILC blocks * 4 waves stride over tail rows of batch b, 2x unrolled
        for (int t = t0 + chunk * 4 + wave; t < T; t += 2 * TAILC * 4) {
            f32x4* dst = (f32x4*)(out + ((size_t)b * T + t) * DIM) + lane;
            __builtin_nontemporal_store(z, dst);
            const int t2 = t + TAILC * 4;
            if (t2 < T) {
                f32x4* dst2 = (f32x4*)(out + ((size_t)b * T + t2) * DIM) + lane;
                __builtin_nontemporal_store(z, dst2);
            }
        }
    }
}

extern "C" void kernel_launch(void* const* d_in, const int* in_sizes, int n_in,
                              void* d_out, int out_size, void* d_ws, size_t ws_size,
                              hipStream_t stream) {
    const float* x    = (const float*)d_in[0];   // [B,S,D] float32
    const int*   dims = (const int*)d_in[1];     // [B,S,1] int32
    float*       out  = (float*)d_out;           // [B,T,D] float32

    const int T = out_size / (BATCH * DIM);      // padded output length

    int* totals = (int*)d_ws;                    // B ints
    int* csum   = totals + 64;                   // 256B offset keeps 16B alignment

    scan_kernel<<<BATCH, 1024, 0, stream>>>(dims, csum, totals);
    expand_kernel<<<SCATTER_BLOCKS + BATCH * TAILC, 256, 0, stream>>>(
        x, csum, totals, out, T);
}